// Round 1
// baseline (602.224 us; speedup 1.0000x reference)
//
#include <hip/hip_runtime.h>
#include <stdint.h>
#include <math.h>

// ---------------------------------------------------------------------------
// XNOR-Net forward: 3 binarized stride-2 convs + global avg pool + binary FC.
// All convs reduce to alpha^2 * (popcount-based +-1 dot) + bias; signs are
// bit-packed along the reduction dim. Epilogues/alphas/pool/FC in f64 so sign
// decisions match a float64 numpy reference (counts themselves are exact ints).
// ---------------------------------------------------------------------------

// ws layout (bytes)
#define A_OFF      0ull        // double[4]  alphas (mean|w|)
#define WM1_OFF    1024ull     // uint32[64]       layer1 weight sign masks (27 bits)
#define WP2_OFF    2048ull     // u64[128*9]       layer2 packed weight signs
#define WP3_OFF    16384ull    // u64[256*9*2]     layer3 packed weight signs
#define WFP_OFF    65536ull    // u64[1000*4]      fc packed weight signs
#define SP_OFF     98304ull    // u64[32*4]        pooled sign bits
#define P1_OFF     102400ull   // u64[32*112*112]  layer1 out signs (bit=co)
#define P2_OFF     3313664ull  // u64[32*56*56*2]  layer2 out signs
#define H3_OFF     4919296ull  // float[32*784*256] layer3 clipped values [n][hw][co]

__global__ void k_alphas(const float* w1, const float* w2, const float* w3,
                         const float* wf, double* alphas) {
    __shared__ double sd[256];
    const float* w; int n;
    if (blockIdx.x == 0)      { w = w1; n = 64*3*9; }
    else if (blockIdx.x == 1) { w = w2; n = 128*64*9; }
    else if (blockIdx.x == 2) { w = w3; n = 256*128*9; }
    else                      { w = wf; n = 1000*256; }
    double s = 0.0;
    for (int i = threadIdx.x; i < n; i += 256) s += fabs((double)w[i]);
    sd[threadIdx.x] = s; __syncthreads();
    for (int off = 128; off > 0; off >>= 1) {
        if (threadIdx.x < off) sd[threadIdx.x] += sd[threadIdx.x + off];
        __syncthreads();
    }
    if (threadIdx.x == 0) alphas[blockIdx.x] = sd[0] / (double)n;
}

__global__ void k_pack(const float* w1, const float* w2, const float* w3, const float* wf,
                       uint32_t* wm1, uint64_t* wp2, uint64_t* wp3, uint64_t* wfp) {
    int id = blockIdx.x * 256 + threadIdx.x;
    if (id < 64) {
        int co = id; uint32_t m = 0;
        for (int t = 0; t < 27; t++) {
            int ci = t / 9, r = t % 9, kh = r / 3, kw = r % 3;
            if (w1[((co*3 + ci)*3 + kh)*3 + kw] >= 0.f) m |= (1u << t);
        }
        wm1[co] = m;
    } else if (id < 64 + 1152) {
        int rel = id - 64; int co = rel / 9, tap = rel % 9;
        int kh = tap / 3, kw = tap % 3;
        uint64_t m = 0;
        for (int ci = 0; ci < 64; ci++)
            if (w2[((co*64 + ci)*3 + kh)*3 + kw] >= 0.f) m |= (1ull << ci);
        wp2[co*9 + tap] = m;
    } else if (id < 64 + 1152 + 4608) {
        int rel = id - 1216; int co = rel / 18; int r = rel % 18;
        int tap = r / 2, half = r % 2; int kh = tap / 3, kw = tap % 3;
        uint64_t m = 0;
        for (int b = 0; b < 64; b++) {
            int ci = half*64 + b;
            if (w3[((co*128 + ci)*3 + kh)*3 + kw] >= 0.f) m |= (1ull << b);
        }
        wp3[(co*9 + tap)*2 + half] = m;
    } else if (id < 64 + 1152 + 4608 + 4000) {
        int rel = id - 5824; int o = rel / 4, j = rel % 4;
        uint64_t m = 0;
        for (int b = 0; b < 64; b++)
            if (wf[o*256 + j*64 + b] >= 0.f) m |= (1ull << b);
        wfp[o*4 + j] = m;
    }
}

// Layer 1: x[32,3,224,224] f32 -> p1[n,112,112] u64 (bit co = sign of h1)
__global__ void k_conv1(const float* __restrict__ x, const float* __restrict__ b1,
                        const double* __restrict__ alphas,
                        const uint32_t* __restrict__ wm1g, uint64_t* __restrict__ p1) {
    __shared__ uint32_t wm[64];
    if (threadIdx.x < 64) wm[threadIdx.x] = wm1g[threadIdx.x];
    __syncthreads();
    int idx = blockIdx.x * 256 + threadIdx.x;
    if (idx >= 32*112*112) return;
    int wo = idx % 112, t1 = idx / 112;
    int ho = t1 % 112, n = t1 / 112;
    uint32_t xm = 0, vm = 0;
    #pragma unroll
    for (int ci = 0; ci < 3; ci++)
        #pragma unroll
        for (int kh = 0; kh < 3; kh++) {
            int hi = 2*ho + kh - 1;
            if ((unsigned)hi >= 224u) continue;
            #pragma unroll
            for (int kw = 0; kw < 3; kw++) {
                int wi = 2*wo + kw - 1;
                if ((unsigned)wi >= 224u) continue;
                int t = ci*9 + kh*3 + kw;
                vm |= (1u << t);
                if (x[((n*3 + ci)*224 + hi)*224 + wi] >= 0.f) xm |= (1u << t);
            }
        }
    int V = __popc(vm);
    double a = alphas[0]; double a2 = a * a;
    uint64_t bits = 0;
    for (int co = 0; co < 64; co++) {
        int m = __popc((~(xm ^ wm[co])) & vm);       // matches
        double h = a2 * (double)(2*m - V) + (double)b1[co];
        if (h >= 0.0) bits |= (1ull << co);
    }
    p1[idx] = bits;
}

// Layer 2: p1 -> p2[n,56,56][2] u64 (128 co bits)
__global__ void k_conv2(const uint64_t* __restrict__ p1, const float* __restrict__ b2,
                        const double* __restrict__ alphas,
                        const uint64_t* __restrict__ wp2g, uint64_t* __restrict__ p2) {
    __shared__ uint64_t wp[128*9];
    for (int i = threadIdx.x; i < 1152; i += 256) wp[i] = wp2g[i];
    __syncthreads();
    int idx = blockIdx.x * 256 + threadIdx.x;
    if (idx >= 32*56*56) return;
    int wo = idx % 56, t1 = idx / 56;
    int ho = t1 % 56, n = t1 / 56;
    uint64_t xv[9]; uint64_t vmask[9]; int V = 0;
    #pragma unroll
    for (int kh = 0; kh < 3; kh++)
        #pragma unroll
        for (int kw = 0; kw < 3; kw++) {
            int t = kh*3 + kw;
            int hi = 2*ho + kh - 1, wi = 2*wo + kw - 1;
            bool ok = ((unsigned)hi < 112u) && ((unsigned)wi < 112u);
            vmask[t] = ok ? ~0ull : 0ull;
            xv[t] = ok ? p1[(n*112 + hi)*112 + wi] : 0ull;
            V += ok ? 1 : 0;
        }
    double a = alphas[1]; double a2 = a * a;
    int base = 64 * V;
    uint64_t bits0 = 0, bits1 = 0;
    for (int co = 0; co < 128; co++) {
        int m = 0;
        #pragma unroll
        for (int t = 0; t < 9; t++)
            m += __popcll((xv[t] ^ wp[co*9 + t]) & vmask[t]);
        double h = a2 * (double)(base - 2*m) + (double)b2[co];
        if (h >= 0.0) { if (co < 64) bits0 |= 1ull << co; else bits1 |= 1ull << (co-64); }
    }
    p2[(size_t)idx*2]     = bits0;
    p2[(size_t)idx*2 + 1] = bits1;
}

// Layer 3: p2 -> h3[n][hw][co] f32 clipped values (needed by avg pool)
__global__ void k_conv3(const uint64_t* __restrict__ p2, const float* __restrict__ b3,
                        const double* __restrict__ alphas,
                        const uint64_t* __restrict__ wp3g, float* __restrict__ h3) {
    __shared__ uint64_t wp[256*18];   // 36 KB
    for (int i = threadIdx.x; i < 4608; i += 256) wp[i] = wp3g[i];
    __syncthreads();
    int idx = blockIdx.x * 256 + threadIdx.x;
    if (idx >= 32*28*28) return;
    int wo = idx % 28, t1 = idx / 28;
    int ho = t1 % 28, n = t1 / 28;
    uint64_t xv0[9], xv1[9], vmask[9]; int V = 0;
    #pragma unroll
    for (int kh = 0; kh < 3; kh++)
        #pragma unroll
        for (int kw = 0; kw < 3; kw++) {
            int t = kh*3 + kw;
            int hi = 2*ho + kh - 1, wi = 2*wo + kw - 1;
            bool ok = ((unsigned)hi < 56u) && ((unsigned)wi < 56u);
            vmask[t] = ok ? ~0ull : 0ull;
            int p = ((n*56 + hi)*56 + wi) * 2;
            xv0[t] = ok ? p2[p]     : 0ull;
            xv1[t] = ok ? p2[p + 1] : 0ull;
            V += ok ? 1 : 0;
        }
    double a = alphas[2]; double a2 = a * a;
    int base = 128 * V;
    float* out = h3 + (size_t)idx * 256;
    for (int co = 0; co < 256; co++) {
        int m = 0;
        #pragma unroll
        for (int t = 0; t < 9; t++) {
            m += __popcll((xv0[t] ^ wp[co*18 + t*2    ]) & vmask[t]);
            m += __popcll((xv1[t] ^ wp[co*18 + t*2 + 1]) & vmask[t]);
        }
        double h = a2 * (double)(base - 2*m) + (double)b3[co];
        h = fmin(fmax(h, -1.0), 1.0);
        out[co] = (float)h;
    }
}

// Global avg pool over 784 positions -> packed sign bits sp[n][4]
__global__ void k_pool(const float* __restrict__ h3, uint64_t* __restrict__ sp) {
    int n = blockIdx.x; int co = threadIdx.x;   // 256 threads = 256 channels
    double s = 0.0;
    const float* base = h3 + (size_t)n * 784 * 256 + co;
    for (int hw = 0; hw < 784; hw++) s += (double)base[hw * 256];
    double p = s / 784.0;
    uint64_t bal = __ballot(p >= 0.0);
    if ((co & 63) == 0) sp[n*4 + (co >> 6)] = bal;
}

// FC: out[n,o] = a4^2 * (256 - 2*popcount_xor) + bf[o]
__global__ void k_fc(const uint64_t* __restrict__ sp, const uint64_t* __restrict__ wfp,
                     const float* __restrict__ bf, const double* __restrict__ alphas,
                     float* __restrict__ out) {
    int idx = blockIdx.x * 256 + threadIdx.x;
    if (idx >= 32*1000) return;
    int o = idx % 1000, n = idx / 1000;
    int m = 0;
    #pragma unroll
    for (int j = 0; j < 4; j++)
        m += __popcll(sp[n*4 + j] ^ wfp[o*4 + j]);
    double a = alphas[3];
    double r = a * a * (double)(256 - 2*m) + (double)bf[o];
    out[idx] = (float)r;
}

extern "C" void kernel_launch(void* const* d_in, const int* in_sizes, int n_in,
                              void* d_out, int out_size, void* d_ws, size_t ws_size,
                              hipStream_t stream) {
    const float* x  = (const float*)d_in[0];
    const float* w1 = (const float*)d_in[1];
    const float* b1 = (const float*)d_in[2];
    const float* w2 = (const float*)d_in[3];
    const float* b2 = (const float*)d_in[4];
    const float* w3 = (const float*)d_in[5];
    const float* b3 = (const float*)d_in[6];
    const float* wf = (const float*)d_in[7];
    const float* bf = (const float*)d_in[8];

    char* ws = (char*)d_ws;
    double*   alphas = (double*)  (ws + A_OFF);
    uint32_t* wm1    = (uint32_t*)(ws + WM1_OFF);
    uint64_t* wp2    = (uint64_t*)(ws + WP2_OFF);
    uint64_t* wp3    = (uint64_t*)(ws + WP3_OFF);
    uint64_t* wfp    = (uint64_t*)(ws + WFP_OFF);
    uint64_t* sp     = (uint64_t*)(ws + SP_OFF);
    uint64_t* p1     = (uint64_t*)(ws + P1_OFF);
    uint64_t* p2     = (uint64_t*)(ws + P2_OFF);
    float*    h3     = (float*)   (ws + H3_OFF);
    float*    out    = (float*)   d_out;

    hipLaunchKernelGGL(k_alphas, dim3(4),    dim3(256), 0, stream, w1, w2, w3, wf, alphas);
    hipLaunchKernelGGL(k_pack,   dim3(39),   dim3(256), 0, stream, w1, w2, w3, wf, wm1, wp2, wp3, wfp);
    hipLaunchKernelGGL(k_conv1,  dim3(1568), dim3(256), 0, stream, x, b1, alphas, wm1, p1);
    hipLaunchKernelGGL(k_conv2,  dim3(392),  dim3(256), 0, stream, p1, b2, alphas, wp2, p2);
    hipLaunchKernelGGL(k_conv3,  dim3(98),   dim3(256), 0, stream, p2, b3, alphas, wp3, h3);
    hipLaunchKernelGGL(k_pool,   dim3(32),   dim3(256), 0, stream, h3, sp);
    hipLaunchKernelGGL(k_fc,     dim3(125),  dim3(256), 0, stream, sp, wfp, bf, alphas, out);
}

// Round 2
// 310.669 us; speedup vs baseline: 1.9385x; 1.9385x over previous
//
#include <hip/hip_runtime.h>
#include <stdint.h>
#include <math.h>

// ---------------------------------------------------------------------------
// XNOR-Net forward: 3 binarized stride-2 convs + global avg pool + binary FC.
// All convs reduce to alpha^2 * (popcount-based +-1 dot) + bias; signs are
// bit-packed along the reduction dim. Epilogues/alphas/pool/FC in f64 so sign
// decisions match a float64 numpy reference (counts themselves are exact ints).
// R2: alpha reduction parallelized (128-block deterministic tree, 4-acc
// unroll) — R1 profile showed it at 470us/dispatch, 80% of runtime.
// ---------------------------------------------------------------------------

// ws layout (bytes)
#define A_OFF      0ull        // double[4]  alphas (mean|w|)
#define WM1_OFF    1024ull     // uint32[64]       layer1 weight sign masks (27 bits)
#define WP2_OFF    2048ull     // u64[128*9]       layer2 packed weight signs
#define WP3_OFF    16384ull    // u64[256*9*2]     layer3 packed weight signs
#define WFP_OFF    65536ull    // u64[1000*4]      fc packed weight signs
#define SP_OFF     98304ull    // u64[32*4]        pooled sign bits
#define PART_OFF   100352ull   // double[128]      alpha partial sums
#define P1_OFF     102400ull   // u64[32*112*112]  layer1 out signs (bit=co)
#define P2_OFF     3313664ull  // u64[32*56*56*2]  layer2 out signs
#define H3_OFF     4919296ull  // float[32*784*256] layer3 clipped values [n][hw][co]

// Stage 1: 128 blocks = 4 tensors x 32 chunks. 4 independent accumulators
// keep 4 loads in flight (single-acc serial chain was the R1 470us bug).
__global__ void k_alpha_part(const float* __restrict__ w1, const float* __restrict__ w2,
                             const float* __restrict__ w3, const float* __restrict__ wf,
                             double* __restrict__ part) {
    __shared__ double sd[256];
    int t = blockIdx.x >> 5, c = blockIdx.x & 31;
    const float* w; int n;
    if (t == 0)      { w = w1; n = 64*3*9; }
    else if (t == 1) { w = w2; n = 128*64*9; }
    else if (t == 2) { w = w3; n = 256*128*9; }
    else             { w = wf; n = 1000*256; }
    int per = (n + 31) / 32;
    int lo = c * per, hi = min(n, lo + per);
    double s0 = 0.0, s1 = 0.0, s2 = 0.0, s3 = 0.0;
    int i = lo + threadIdx.x;
    for (; i + 768 < hi; i += 1024) {
        s0 += fabs((double)w[i]);
        s1 += fabs((double)w[i + 256]);
        s2 += fabs((double)w[i + 512]);
        s3 += fabs((double)w[i + 768]);
    }
    for (; i < hi; i += 256) s0 += fabs((double)w[i]);
    sd[threadIdx.x] = (s0 + s1) + (s2 + s3);
    __syncthreads();
    for (int off = 128; off > 0; off >>= 1) {
        if (threadIdx.x < off) sd[threadIdx.x] += sd[threadIdx.x + off];
        __syncthreads();
    }
    if (threadIdx.x == 0) part[blockIdx.x] = sd[0];
}

// Stage 2: fixed-order serial sum of 32 partials per tensor (deterministic).
__global__ void k_alpha_fin(const double* __restrict__ part, double* __restrict__ alphas) {
    int t = threadIdx.x;
    if (t < 4) {
        const int ns[4] = {64*3*9, 128*64*9, 256*128*9, 1000*256};
        double s = 0.0;
        for (int j = 0; j < 32; j++) s += part[t*32 + j];
        alphas[t] = s / (double)ns[t];
    }
}

__global__ void k_pack(const float* w1, const float* w2, const float* w3, const float* wf,
                       uint32_t* wm1, uint64_t* wp2, uint64_t* wp3, uint64_t* wfp) {
    int id = blockIdx.x * 256 + threadIdx.x;
    if (id < 64) {
        int co = id; uint32_t m = 0;
        for (int t = 0; t < 27; t++) {
            int ci = t / 9, r = t % 9, kh = r / 3, kw = r % 3;
            if (w1[((co*3 + ci)*3 + kh)*3 + kw] >= 0.f) m |= (1u << t);
        }
        wm1[co] = m;
    } else if (id < 64 + 1152) {
        int rel = id - 64; int co = rel / 9, tap = rel % 9;
        int kh = tap / 3, kw = tap % 3;
        uint64_t m = 0;
        for (int ci = 0; ci < 64; ci++)
            if (w2[((co*64 + ci)*3 + kh)*3 + kw] >= 0.f) m |= (1ull << ci);
        wp2[co*9 + tap] = m;
    } else if (id < 64 + 1152 + 4608) {
        int rel = id - 1216; int co = rel / 18; int r = rel % 18;
        int tap = r / 2, half = r % 2; int kh = tap / 3, kw = tap % 3;
        uint64_t m = 0;
        for (int b = 0; b < 64; b++) {
            int ci = half*64 + b;
            if (w3[((co*128 + ci)*3 + kh)*3 + kw] >= 0.f) m |= (1ull << b);
        }
        wp3[(co*9 + tap)*2 + half] = m;
    } else if (id < 64 + 1152 + 4608 + 4000) {
        int rel = id - 5824; int o = rel / 4, j = rel % 4;
        uint64_t m = 0;
        for (int b = 0; b < 64; b++)
            if (wf[o*256 + j*64 + b] >= 0.f) m |= (1ull << b);
        wfp[o*4 + j] = m;
    }
}

// Layer 1: x[32,3,224,224] f32 -> p1[n,112,112] u64 (bit co = sign of h1)
__global__ void k_conv1(const float* __restrict__ x, const float* __restrict__ b1,
                        const double* __restrict__ alphas,
                        const uint32_t* __restrict__ wm1g, uint64_t* __restrict__ p1) {
    __shared__ uint32_t wm[64];
    if (threadIdx.x < 64) wm[threadIdx.x] = wm1g[threadIdx.x];
    __syncthreads();
    int idx = blockIdx.x * 256 + threadIdx.x;
    if (idx >= 32*112*112) return;
    int wo = idx % 112, t1 = idx / 112;
    int ho = t1 % 112, n = t1 / 112;
    uint32_t xm = 0, vm = 0;
    #pragma unroll
    for (int ci = 0; ci < 3; ci++)
        #pragma unroll
        for (int kh = 0; kh < 3; kh++) {
            int hi = 2*ho + kh - 1;
            if ((unsigned)hi >= 224u) continue;
            #pragma unroll
            for (int kw = 0; kw < 3; kw++) {
                int wi = 2*wo + kw - 1;
                if ((unsigned)wi >= 224u) continue;
                int t = ci*9 + kh*3 + kw;
                vm |= (1u << t);
                if (x[((n*3 + ci)*224 + hi)*224 + wi] >= 0.f) xm |= (1u << t);
            }
        }
    int V = __popc(vm);
    double a = alphas[0]; double a2 = a * a;
    uint64_t bits = 0;
    for (int co = 0; co < 64; co++) {
        int m = __popc((~(xm ^ wm[co])) & vm);       // matches
        double h = a2 * (double)(2*m - V) + (double)b1[co];
        if (h >= 0.0) bits |= (1ull << co);
    }
    p1[idx] = bits;
}

// Layer 2: p1 -> p2[n,56,56][2] u64 (128 co bits)
__global__ void k_conv2(const uint64_t* __restrict__ p1, const float* __restrict__ b2,
                        const double* __restrict__ alphas,
                        const uint64_t* __restrict__ wp2g, uint64_t* __restrict__ p2) {
    __shared__ uint64_t wp[128*9];
    for (int i = threadIdx.x; i < 1152; i += 256) wp[i] = wp2g[i];
    __syncthreads();
    int idx = blockIdx.x * 256 + threadIdx.x;
    if (idx >= 32*56*56) return;
    int wo = idx % 56, t1 = idx / 56;
    int ho = t1 % 56, n = t1 / 56;
    uint64_t xv[9]; uint64_t vmask[9]; int V = 0;
    #pragma unroll
    for (int kh = 0; kh < 3; kh++)
        #pragma unroll
        for (int kw = 0; kw < 3; kw++) {
            int t = kh*3 + kw;
            int hi = 2*ho + kh - 1, wi = 2*wo + kw - 1;
            bool ok = ((unsigned)hi < 112u) && ((unsigned)wi < 112u);
            vmask[t] = ok ? ~0ull : 0ull;
            xv[t] = ok ? p1[(n*112 + hi)*112 + wi] : 0ull;
            V += ok ? 1 : 0;
        }
    double a = alphas[1]; double a2 = a * a;
    int base = 64 * V;
    uint64_t bits0 = 0, bits1 = 0;
    for (int co = 0; co < 128; co++) {
        int m = 0;
        #pragma unroll
        for (int t = 0; t < 9; t++)
            m += __popcll((xv[t] ^ wp[co*9 + t]) & vmask[t]);
        double h = a2 * (double)(base - 2*m) + (double)b2[co];
        if (h >= 0.0) { if (co < 64) bits0 |= 1ull << co; else bits1 |= 1ull << (co-64); }
    }
    p2[(size_t)idx*2]     = bits0;
    p2[(size_t)idx*2 + 1] = bits1;
}

// Layer 3: p2 -> h3[n][hw][co] f32 clipped values (needed by avg pool)
__global__ void k_conv3(const uint64_t* __restrict__ p2, const float* __restrict__ b3,
                        const double* __restrict__ alphas,
                        const uint64_t* __restrict__ wp3g, float* __restrict__ h3) {
    __shared__ uint64_t wp[256*18];   // 36 KB
    for (int i = threadIdx.x; i < 4608; i += 256) wp[i] = wp3g[i];
    __syncthreads();
    int idx = blockIdx.x * 256 + threadIdx.x;
    if (idx >= 32*28*28) return;
    int wo = idx % 28, t1 = idx / 28;
    int ho = t1 % 28, n = t1 / 28;
    uint64_t xv0[9], xv1[9], vmask[9]; int V = 0;
    #pragma unroll
    for (int kh = 0; kh < 3; kh++)
        #pragma unroll
        for (int kw = 0; kw < 3; kw++) {
            int t = kh*3 + kw;
            int hi = 2*ho + kh - 1, wi = 2*wo + kw - 1;
            bool ok = ((unsigned)hi < 56u) && ((unsigned)wi < 56u);
            vmask[t] = ok ? ~0ull : 0ull;
            int p = ((n*56 + hi)*56 + wi) * 2;
            xv0[t] = ok ? p2[p]     : 0ull;
            xv1[t] = ok ? p2[p + 1] : 0ull;
            V += ok ? 1 : 0;
        }
    double a = alphas[2]; double a2 = a * a;
    int base = 128 * V;
    float* out = h3 + (size_t)idx * 256;
    for (int co = 0; co < 256; co++) {
        int m = 0;
        #pragma unroll
        for (int t = 0; t < 9; t++) {
            m += __popcll((xv0[t] ^ wp[co*18 + t*2    ]) & vmask[t]);
            m += __popcll((xv1[t] ^ wp[co*18 + t*2 + 1]) & vmask[t]);
        }
        double h = a2 * (double)(base - 2*m) + (double)b3[co];
        h = fmin(fmax(h, -1.0), 1.0);
        out[co] = (float)h;
    }
}

// Global avg pool over 784 positions -> packed sign bits sp[n][4]
__global__ void k_pool(const float* __restrict__ h3, uint64_t* __restrict__ sp) {
    int n = blockIdx.x; int co = threadIdx.x;   // 256 threads = 256 channels
    double s = 0.0;
    const float* base = h3 + (size_t)n * 784 * 256 + co;
    for (int hw = 0; hw < 784; hw++) s += (double)base[hw * 256];
    double p = s / 784.0;
    uint64_t bal = __ballot(p >= 0.0);
    if ((co & 63) == 0) sp[n*4 + (co >> 6)] = bal;
}

// FC: out[n,o] = a4^2 * (256 - 2*popcount_xor) + bf[o]
__global__ void k_fc(const uint64_t* __restrict__ sp, const uint64_t* __restrict__ wfp,
                     const float* __restrict__ bf, const double* __restrict__ alphas,
                     float* __restrict__ out) {
    int idx = blockIdx.x * 256 + threadIdx.x;
    if (idx >= 32*1000) return;
    int o = idx % 1000, n = idx / 1000;
    int m = 0;
    #pragma unroll
    for (int j = 0; j < 4; j++)
        m += __popcll(sp[n*4 + j] ^ wfp[o*4 + j]);
    double a = alphas[3];
    double r = a * a * (double)(256 - 2*m) + (double)bf[o];
    out[idx] = (float)r;
}

extern "C" void kernel_launch(void* const* d_in, const int* in_sizes, int n_in,
                              void* d_out, int out_size, void* d_ws, size_t ws_size,
                              hipStream_t stream) {
    const float* x  = (const float*)d_in[0];
    const float* w1 = (const float*)d_in[1];
    const float* b1 = (const float*)d_in[2];
    const float* w2 = (const float*)d_in[3];
    const float* b2 = (const float*)d_in[4];
    const float* w3 = (const float*)d_in[5];
    const float* b3 = (const float*)d_in[6];
    const float* wf = (const float*)d_in[7];
    const float* bf = (const float*)d_in[8];

    char* ws = (char*)d_ws;
    double*   alphas = (double*)  (ws + A_OFF);
    uint32_t* wm1    = (uint32_t*)(ws + WM1_OFF);
    uint64_t* wp2    = (uint64_t*)(ws + WP2_OFF);
    uint64_t* wp3    = (uint64_t*)(ws + WP3_OFF);
    uint64_t* wfp    = (uint64_t*)(ws + WFP_OFF);
    uint64_t* sp     = (uint64_t*)(ws + SP_OFF);
    double*   part   = (double*)  (ws + PART_OFF);
    uint64_t* p1     = (uint64_t*)(ws + P1_OFF);
    uint64_t* p2     = (uint64_t*)(ws + P2_OFF);
    float*    h3     = (float*)   (ws + H3_OFF);
    float*    out    = (float*)   d_out;

    hipLaunchKernelGGL(k_alpha_part, dim3(128),  dim3(256), 0, stream, w1, w2, w3, wf, part);
    hipLaunchKernelGGL(k_alpha_fin,  dim3(1),    dim3(64),  0, stream, part, alphas);
    hipLaunchKernelGGL(k_pack,       dim3(39),   dim3(256), 0, stream, w1, w2, w3, wf, wm1, wp2, wp3, wfp);
    hipLaunchKernelGGL(k_conv1,      dim3(1568), dim3(256), 0, stream, x, b1, alphas, wm1, p1);
    hipLaunchKernelGGL(k_conv2,      dim3(392),  dim3(256), 0, stream, p1, b2, alphas, wp2, p2);
    hipLaunchKernelGGL(k_conv3,      dim3(98),   dim3(256), 0, stream, p2, b3, alphas, wp3, h3);
    hipLaunchKernelGGL(k_pool,       dim3(32),   dim3(256), 0, stream, h3, sp);
    hipLaunchKernelGGL(k_fc,         dim3(125),  dim3(256), 0, stream, sp, wfp, bf, alphas, out);
}

// Round 4
// 156.777 us; speedup vs baseline: 3.8413x; 1.9816x over previous
//
#include <hip/hip_runtime.h>
#include <stdint.h>
#include <math.h>

// ---------------------------------------------------------------------------
// XNOR-Net forward: 3 binarized stride-2 convs + global avg pool + binary FC.
// Convs = alpha^2 * (xor-popcount dot) + bias on bit-packed signs; epilogues
// and alphas in f64 over exact integer counts (absmax 0.0 in R1/R2).
// R4: fixes R3's border bug in conv3pool — with even input (56), stride 2,
// pad 1, ONLY ho==0 / wo==0 lose a tap; ho==27/wo==27 are fully interior
// (hi,wi <= 55 < 56). R3 wrongly treated 27 as a border row/col.
// ---------------------------------------------------------------------------

// ws layout (bytes)
#define A_OFF      0ull        // double[4]        alphas (mean|w|)
#define WM1_OFF    1024ull     // uint32[64]       layer1 weight sign masks (27 bits)
#define WP2_OFF    2048ull     // u64[128*9]       layer2 packed weight signs [co][tap]
#define WP3T_OFF   16384ull    // u64[18*256]      layer3 packed weights TRANSPOSED [tap*2+half][co]
#define WFP_OFF    65536ull    // u64[1000*4]      fc packed weight signs
#define SP_OFF     98304ull    // u64[32*4]        pooled sign bits
#define PART_OFF   100352ull   // double[128]      alpha partial sums
#define P1_OFF     102400ull   // u64[32*112*112]  layer1 out signs (bit=co)
#define P2_OFF     3313664ull  // u32[32*56*56*4]  layer2 out signs (quarter q = co 32q..)
#define POOLP_OFF  4919296ull  // double[32*28*256] conv3 row-partial pool sums

// ---- alphas: 128-block deterministic tree, 4 accumulators ----
__global__ void k_alpha_part(const float* __restrict__ w1, const float* __restrict__ w2,
                             const float* __restrict__ w3, const float* __restrict__ wf,
                             double* __restrict__ part) {
    __shared__ double sd[256];
    int t = blockIdx.x >> 5, c = blockIdx.x & 31;
    const float* w; int n;
    if (t == 0)      { w = w1; n = 64*3*9; }
    else if (t == 1) { w = w2; n = 128*64*9; }
    else if (t == 2) { w = w3; n = 256*128*9; }
    else             { w = wf; n = 1000*256; }
    int per = (n + 31) / 32;
    int lo = c * per, hi = min(n, lo + per);
    double s0 = 0.0, s1 = 0.0, s2 = 0.0, s3 = 0.0;
    int i = lo + threadIdx.x;
    for (; i + 768 < hi; i += 1024) {
        s0 += fabs((double)w[i]);
        s1 += fabs((double)w[i + 256]);
        s2 += fabs((double)w[i + 512]);
        s3 += fabs((double)w[i + 768]);
    }
    for (; i < hi; i += 256) s0 += fabs((double)w[i]);
    sd[threadIdx.x] = (s0 + s1) + (s2 + s3);
    __syncthreads();
    for (int off = 128; off > 0; off >>= 1) {
        if (threadIdx.x < off) sd[threadIdx.x] += sd[threadIdx.x + off];
        __syncthreads();
    }
    if (threadIdx.x == 0) part[blockIdx.x] = sd[0];
}

__global__ void k_alpha_fin(const double* __restrict__ part, double* __restrict__ alphas) {
    int t = threadIdx.x;
    if (t < 4) {
        const int ns[4] = {64*3*9, 128*64*9, 256*128*9, 1000*256};
        double s = 0.0;
        for (int j = 0; j < 32; j++) s += part[t*32 + j];
        alphas[t] = s / (double)ns[t];
    }
}

// ---- pack: one lane per bit, __ballot assembles each u64 word ----
__global__ void k_pack(const float* __restrict__ w1, const float* __restrict__ w2,
                       const float* __restrict__ w3, const float* __restrict__ wf,
                       uint32_t* __restrict__ wm1, uint64_t* __restrict__ wp2,
                       uint64_t* __restrict__ wp3t, uint64_t* __restrict__ wfp) {
    int gid = blockIdx.x * 256 + threadIdx.x;
    int lane = threadIdx.x & 63;
    if (blockIdx.x < 288) {
        int word = gid >> 6;                 // co*9 + tap
        int co = word / 9, tap = word % 9;
        int kh = tap / 3, kw = tap % 3;
        bool pos = w2[((co*64 + lane)*3 + kh)*3 + kw] >= 0.f;
        uint64_t b = __ballot(pos);
        if (lane == 0) wp2[word] = b;
    } else if (blockIdx.x < 1440) {
        int rel = gid - 73728;
        int word = rel >> 6;                 // co*18 + tap*2 + half
        int co = word / 18, r = word % 18;
        int tap = r / 2, half = r % 2;
        int kh = tap / 3, kw = tap % 3;
        int ci = half*64 + lane;
        bool pos = w3[((co*128 + ci)*3 + kh)*3 + kw] >= 0.f;
        uint64_t b = __ballot(pos);
        if (lane == 0) wp3t[(tap*2 + half)*256 + co] = b;
    } else if (blockIdx.x < 2440) {
        int rel = gid - 368640;
        int word = rel >> 6;                 // o*4 + j
        int o = word / 4, j = word % 4;
        bool pos = wf[o*256 + j*64 + lane] >= 0.f;
        uint64_t b = __ballot(pos);
        if (lane == 0) wfp[word] = b;
    } else {
        int co = threadIdx.x;
        if (co < 64) {
            uint32_t m = 0;
            for (int t = 0; t < 27; t++) {
                int ci = t / 9, r = t % 9, kh = r / 3, kw = r % 3;
                if (w1[((co*3 + ci)*3 + kh)*3 + kw] >= 0.f) m |= (1u << t);
            }
            wm1[co] = m;
        }
    }
}

// ---- Layer 1: x[32,3,224,224] f32 -> p1[n,112,112] u64 (bit=co) ----
__global__ void k_conv1(const float* __restrict__ x, const float* __restrict__ b1,
                        const double* __restrict__ alphas,
                        const uint32_t* __restrict__ wm1g, uint64_t* __restrict__ p1) {
    __shared__ uint32_t wm[64];
    if (threadIdx.x < 64) wm[threadIdx.x] = wm1g[threadIdx.x];
    __syncthreads();
    int idx = blockIdx.x * 256 + threadIdx.x;
    if (idx >= 32*112*112) return;
    int wo = idx % 112, t1 = idx / 112;
    int ho = t1 % 112, n = t1 / 112;
    uint32_t xm = 0, vm = 0;
    #pragma unroll
    for (int ci = 0; ci < 3; ci++)
        #pragma unroll
        for (int kh = 0; kh < 3; kh++) {
            int hi = 2*ho + kh - 1;
            if ((unsigned)hi >= 224u) continue;
            #pragma unroll
            for (int kw = 0; kw < 3; kw++) {
                int wi = 2*wo + kw - 1;
                if ((unsigned)wi >= 224u) continue;
                int t = ci*9 + kh*3 + kw;
                vm |= (1u << t);
                if (x[((n*3 + ci)*224 + hi)*224 + wi] >= 0.f) xm |= (1u << t);
            }
        }
    int V = __popc(vm);
    double a = alphas[0]; double a2 = a * a;
    uint64_t bits = 0;
    for (int co = 0; co < 64; co++) {
        int m = __popc((~(xm ^ wm[co])) & vm);       // matches
        double h = a2 * (double)(2*m - V) + (double)b1[co];
        if (h >= 0.0) bits |= (1ull << co);
    }
    p1[idx] = bits;
}

// ---- Layer 2: p1 -> p2 u32 quarters. wave q = co quarter, lane = position. ----
__global__ void k_conv2(const uint64_t* __restrict__ p1, const float* __restrict__ b2,
                        const double* __restrict__ alphas,
                        const uint64_t* __restrict__ wp2g, uint32_t* __restrict__ p2) {
    __shared__ uint64_t wp[128*9];
    for (int i = threadIdx.x; i < 1152; i += 256) wp[i] = wp2g[i];
    __syncthreads();
    int q = threadIdx.x >> 6;                       // co quarter (wave-uniform)
    int pos = blockIdx.x * 64 + (threadIdx.x & 63); // output position
    int wo = pos % 56, t1 = pos / 56;
    int ho = t1 % 56, n = t1 / 56;
    uint64_t xv[9]; uint64_t vmask[9]; int V = 0;
    #pragma unroll
    for (int kh = 0; kh < 3; kh++)
        #pragma unroll
        for (int kw = 0; kw < 3; kw++) {
            int t = kh*3 + kw;
            int hi = 2*ho + kh - 1, wi = 2*wo + kw - 1;
            bool ok = ((unsigned)hi < 112u) && ((unsigned)wi < 112u);
            vmask[t] = ok ? ~0ull : 0ull;
            xv[t] = ok ? p1[(n*112 + hi)*112 + wi] : 0ull;
            V += ok ? 1 : 0;
        }
    double a = alphas[1]; double a2 = a * a;
    int base = 64 * V;
    uint32_t bits = 0;
    int co0 = q * 32;
    for (int c = 0; c < 32; c++) {
        int co = co0 + c;
        int m = 0;
        #pragma unroll
        for (int t = 0; t < 9; t++)
            m += __popcll((xv[t] ^ wp[co*9 + t]) & vmask[t]);
        double h = a2 * (double)(base - 2*m) + (double)b2[co];
        if (h >= 0.0) bits |= (1u << c);
    }
    p2[pos*4 + q] = bits;
}

// ---- Layer 3 fused with pool partial: block=(n,ho), thread=co.
// Only ho==0 (hi=-1) and wo==0 (wi=-1) are borders: for even input 56,
// ho=27 gives hi in {53,54,55}, all valid. (R3's bug was treating 27 as edge.)
__global__ void k_conv3pool(const uint64_t* __restrict__ p2, const float* __restrict__ b3,
                            const double* __restrict__ alphas,
                            const uint64_t* __restrict__ wp3t, double* __restrict__ partial) {
    __shared__ uint64_t xs[28*18];   // 4032 B, zero-padded row activations
    int n = blockIdx.x / 28, ho = blockIdx.x % 28;
    int co = threadIdx.x;

    uint64_t w[18];
    #pragma unroll
    for (int i = 0; i < 18; i++) w[i] = wp3t[i*256 + co];   // coalesced
    uint32_t P[9];
    #pragma unroll
    for (int t = 0; t < 9; t++) P[t] = __popcll(w[2*t]) + __popcll(w[2*t+1]);

    for (int i = threadIdx.x; i < 504; i += 256) {
        int wo = i / 18, r = i % 18;
        int tap = r / 2, half = r % 2;
        int kh = tap / 3, kw = tap % 3;
        int hi = 2*ho + kh - 1, wi = 2*wo + kw - 1;
        bool ok = ((unsigned)hi < 56u) && ((unsigned)wi < 56u);
        xs[i] = ok ? p2[(size_t)((n*56 + hi)*56 + wi)*2 + half] : 0ull;
    }
    __syncthreads();

    bool htop = (ho == 0);
    int rv = htop ? 2 : 3;
    double a = alphas[2]; double a2 = a * a;
    double bc = (double)b3[co];
    double sum = 0.0;
    for (int wo = 0; wo < 28; wo++) {
        int mm = 0;
        #pragma unroll
        for (int t = 0; t < 18; t++)
            mm += __popcll(xs[wo*18 + t] ^ w[t]);
        bool wl = (wo == 0);
        int cv = wl ? 2 : 3;
        int corr = 0;
        if (htop) corr += P[0] + P[1] + P[2];
        if (wl)   corr += P[0] + P[3] + P[6];
        if (htop && wl) corr -= P[0];
        int dot = 128*(rv*cv) - 2*mm + 2*corr;  // identical integer to masked form
        double h = a2 * (double)dot + bc;
        h = fmin(fmax(h, -1.0), 1.0);
        sum += h;
    }
    partial[(size_t)(n*28 + ho)*256 + co] = sum;
}

// ---- pool finalize: sum 28 row-partials in ho order (same order as R2) ----
__global__ void k_pool_fin(const double* __restrict__ partial, uint64_t* __restrict__ sp) {
    int n = blockIdx.x; int co = threadIdx.x;
    double s = 0.0;
    for (int c = 0; c < 28; c++) s += partial[(size_t)(n*28 + c)*256 + co];
    double p = s / 784.0;
    uint64_t bal = __ballot(p >= 0.0);
    if ((co & 63) == 0) sp[n*4 + (co >> 6)] = bal;
}

// ---- FC ----
__global__ void k_fc(const uint64_t* __restrict__ sp, const uint64_t* __restrict__ wfp,
                     const float* __restrict__ bf, const double* __restrict__ alphas,
                     float* __restrict__ out) {
    int idx = blockIdx.x * 256 + threadIdx.x;
    if (idx >= 32*1000) return;
    int o = idx % 1000, n = idx / 1000;
    int m = 0;
    #pragma unroll
    for (int j = 0; j < 4; j++)
        m += __popcll(sp[n*4 + j] ^ wfp[o*4 + j]);
    double a = alphas[3];
    double r = a * a * (double)(256 - 2*m) + (double)bf[o];
    out[idx] = (float)r;
}

extern "C" void kernel_launch(void* const* d_in, const int* in_sizes, int n_in,
                              void* d_out, int out_size, void* d_ws, size_t ws_size,
                              hipStream_t stream) {
    const float* x  = (const float*)d_in[0];
    const float* w1 = (const float*)d_in[1];
    const float* b1 = (const float*)d_in[2];
    const float* w2 = (const float*)d_in[3];
    const float* b2 = (const float*)d_in[4];
    const float* w3 = (const float*)d_in[5];
    const float* b3 = (const float*)d_in[6];
    const float* wf = (const float*)d_in[7];
    const float* bf = (const float*)d_in[8];

    char* ws = (char*)d_ws;
    double*   alphas = (double*)  (ws + A_OFF);
    uint32_t* wm1    = (uint32_t*)(ws + WM1_OFF);
    uint64_t* wp2    = (uint64_t*)(ws + WP2_OFF);
    uint64_t* wp3t   = (uint64_t*)(ws + WP3T_OFF);
    uint64_t* wfp    = (uint64_t*)(ws + WFP_OFF);
    uint64_t* sp     = (uint64_t*)(ws + SP_OFF);
    double*   part   = (double*)  (ws + PART_OFF);
    uint64_t* p1     = (uint64_t*)(ws + P1_OFF);
    uint32_t* p2     = (uint32_t*)(ws + P2_OFF);
    double*   poolp  = (double*)  (ws + POOLP_OFF);
    float*    out    = (float*)   d_out;

    hipLaunchKernelGGL(k_alpha_part, dim3(128),  dim3(256), 0, stream, w1, w2, w3, wf, part);
    hipLaunchKernelGGL(k_alpha_fin,  dim3(1),    dim3(64),  0, stream, part, alphas);
    hipLaunchKernelGGL(k_pack,       dim3(2441), dim3(256), 0, stream, w1, w2, w3, wf, wm1, wp2, wp3t, wfp);
    hipLaunchKernelGGL(k_conv1,      dim3(1568), dim3(256), 0, stream, x, b1, alphas, wm1, p1);
    hipLaunchKernelGGL(k_conv2,      dim3(1568), dim3(256), 0, stream, p1, b2, alphas, wp2, p2);
    hipLaunchKernelGGL(k_conv3pool,  dim3(896),  dim3(256), 0, stream, (const uint64_t*)p2, b3, alphas, wp3t, poolp);
    hipLaunchKernelGGL(k_pool_fin,   dim3(32),   dim3(256), 0, stream, poolp, sp);
    hipLaunchKernelGGL(k_fc,         dim3(125),  dim3(256), 0, stream, sp, wfp, bf, alphas, out);
}